// Round 5
// baseline (112.212 us; speedup 1.0000x reference)
//
#include <hip/hip_runtime.h>
#include <hip/hip_bf16.h>
#include <cstdint>

// SpatialAttention: x[1,256,16,16,16] -> qkv(768x256) -> 8-head attn(d=32, n=4096) -> proj(256x256)+bias
// ws (bf16): qT[8][4096][32] @0 (pre-scaled by SCALE*log2e), kT[8][4096][32] @2MB,
//            v[8][32][4096] @4MB, attnout[4096][256] @6MB

typedef __bf16 bf16x8 __attribute__((ext_vector_type(8)));
typedef float f32x4 __attribute__((ext_vector_type(4)));
typedef float f32x16 __attribute__((ext_vector_type(16)));
typedef unsigned int u32;
typedef unsigned short u16;
typedef u32 u32x4v __attribute__((ext_vector_type(4)));
typedef u32 u32x2v __attribute__((ext_vector_type(2)));

#define MFMA16(a, b, c) __builtin_amdgcn_mfma_f32_16x16x32_bf16(a, b, c, 0, 0, 0)
#define MFMA32(a, b, c) __builtin_amdgcn_mfma_f32_32x32x16_bf16(a, b, c, 0, 0, 0)

#if __has_builtin(__builtin_amdgcn_exp2f)
#define EXP2(x) __builtin_amdgcn_exp2f(x)
#else
#define EXP2(x) exp2f(x)
#endif

__device__ __forceinline__ u16 f2bf(float f) {
  __bf16 b = (__bf16)f;
  return __builtin_bit_cast(u16, b);
}
__device__ __forceinline__ u32 pk2(float a, float b) {
  return (u32)f2bf(a) | ((u32)f2bf(b) << 16);
}
__device__ __forceinline__ bf16x8 ldfrag(const u16* p) {
  return __builtin_bit_cast(bf16x8, *(const u32x4v*)p);
}
__device__ __forceinline__ void gload_lds16(const void* g, void* l) {
  __builtin_amdgcn_global_load_lds((const __attribute__((address_space(1))) u32*)g,
                                   (__attribute__((address_space(3))) u32*)l, 16, 0, 0);
}
// v_permlane32_swap_b32: a = {a.lo, b.lo}, b = {a.hi, b.hi}
__device__ __forceinline__ void plswap(u32& a, u32& b) {
  asm("v_permlane32_swap_b32 %0, %1" : "+v"(a), "+v"(b));
}
__device__ __forceinline__ f32x16 zero16() {
  f32x16 z;
#pragma unroll
  for (int i = 0; i < 16; ++i) z[i] = 0.0f;
  return z;
}

// ---------------- K1: qkv = w_qkv(768x256) @ x(256x4096), LDS-staged 64o x 128n ----------------
// grid (32 nb, 12 ob), 256 thr = 4 waves: wm = w&1 (2x32o), wn = w>>1 (2x64n)
__global__ __launch_bounds__(256) void qkv_gemm(const float* __restrict__ x,
                                                const float* __restrict__ wq,
                                                u16* __restrict__ qT, u16* __restrict__ kT,
                                                u16* __restrict__ vv) {
  __shared__ __align__(16) u16 Al[64 * 64];
  __shared__ __align__(16) u16 Bl[128 * 64];
  const int t = threadIdx.x;
  const int lane = t & 63, w = t >> 6;
  const int wm = w & 1, wn = w >> 1;
  const int o0 = blockIdx.y * 64, n0 = blockIdx.x * 128;
  const int lr = lane & 15, lg = lane >> 4;
  const float sc = (o0 < 256) ? 0.2550349f : 1.0f;  // q tile: 32^-0.5 * log2(e); uniform per block
  f32x4 acc[2][4];
#pragma unroll
  for (int i = 0; i < 2; ++i)
#pragma unroll
    for (int j = 0; j < 4; ++j)
#pragma unroll
      for (int r = 0; r < 4; ++r) acc[i][j][r] = 0.0f;

  for (int kc = 0; kc < 256; kc += 64) {
    // stage A = w_qkv tile [64 o][64 c], fp32->bf16, scaled
#pragma unroll
    for (int r = 0; r < 4; ++r) {
      int idx = r * 256 + t;
      int o = idx >> 4, c4 = (idx & 15) << 2;
      float4 v4 = *(const float4*)(wq + (size_t)(o0 + o) * 256 + kc + c4);
      u32x2v pkd;
      pkd.x = pk2(v4.x * sc, v4.y * sc);
      pkd.y = pk2(v4.z * sc, v4.w * sc);
      *(u32x2v*)&Al[o * 64 + (c4 ^ ((o & 7) << 3))] = pkd;
    }
    // stage B = x tile transposed to [128 n][64 c]; per-lane 4 channels of one n, packed 8B write
#pragma unroll
    for (int r = 0; r < 8; ++r) {
      int idx = r * 256 + t;
      int n = idx & 127, cg = idx >> 7;
      int c4 = cg << 2;
      const float* xb = x + (size_t)(kc + c4) * 4096 + n0 + n;
      float a0 = xb[0], a1 = xb[4096], a2 = xb[8192], a3 = xb[12288];
      u32x2v pkd;
      pkd.x = pk2(a0, a1);
      pkd.y = pk2(a2, a3);
      *(u32x2v*)&Bl[n * 64 + (c4 ^ ((n & 7) << 3))] = pkd;
    }
    __syncthreads();
#pragma unroll
    for (int kk = 0; kk < 2; ++kk) {
      bf16x8 af[2], bf_[4];
#pragma unroll
      for (int mi = 0; mi < 2; ++mi) {
        int row = wm * 32 + mi * 16 + lr;
        af[mi] = ldfrag(&Al[row * 64 + ((kk * 32 + lg * 8) ^ ((row & 7) << 3))]);
      }
#pragma unroll
      for (int ni = 0; ni < 4; ++ni) {
        int row = wn * 64 + ni * 16 + lr;
        bf_[ni] = ldfrag(&Bl[row * 64 + ((kk * 32 + lg * 8) ^ ((row & 7) << 3))]);
      }
#pragma unroll
      for (int mi = 0; mi < 2; ++mi)
#pragma unroll
        for (int ni = 0; ni < 4; ++ni) acc[mi][ni] = MFMA16(af[mi], bf_[ni], acc[mi][ni]);
    }
    __syncthreads();
  }
  // epilogue: D[o][n]; col n = lr, rows o = obase + r; scatter to q/k/v layouts
#pragma unroll
  for (int mi = 0; mi < 2; ++mi) {
#pragma unroll
    for (int ni = 0; ni < 4; ++ni) {
      int obase = o0 + wm * 32 + mi * 16 + lg * 4;
      int n = n0 + wn * 64 + ni * 16 + lr;
      int part = obase >> 8;
      int oin = obase & 255;
      int h = oin >> 5, c0 = oin & 31;
      if (part == 0) {
        u32x2v pv;
        pv.x = pk2(acc[mi][ni][0], acc[mi][ni][1]);
        pv.y = pk2(acc[mi][ni][2], acc[mi][ni][3]);
        *(u32x2v*)(qT + ((size_t)h * 4096 + n) * 32 + c0) = pv;
      } else if (part == 1) {
        u32x2v pv;
        pv.x = pk2(acc[mi][ni][0], acc[mi][ni][1]);
        pv.y = pk2(acc[mi][ni][2], acc[mi][ni][3]);
        *(u32x2v*)(kT + ((size_t)h * 4096 + n) * 32 + c0) = pv;
      } else {
#pragma unroll
        for (int r = 0; r < 4; ++r)
          vv[((size_t)h * 32 + c0 + r) * 4096 + n] = f2bf(acc[mi][ni][r]);
      }
    }
  }
}

// ---------------- K2: fused flash attention, LDS-free main loop, reg-resident K/V fragments ------
// grid (64 qb, 8 h); 512 thr = 8 waves; wave s: 64 q x kv [s*512, s*512+512)
// fragments loaded straight from global (L2-resident); ds_add_f32 split reduction (8.5 KB LDS)
__global__ __launch_bounds__(512, 4) void attn_fused(const u16* __restrict__ qT,
                                                     const u16* __restrict__ kT,
                                                     const u16* __restrict__ vv,
                                                     u16* __restrict__ aout) {
  __shared__ float red[32 * 64 + 64];  // pbuf[32 c][64 i] + lbuf[64 i]
  float* pbuf = red;
  float* lbuf = red + 32 * 64;
  const int tid = threadIdx.x;
  const int lane = tid & 63, s = tid >> 6;
  const int qb = blockIdx.x, h = blockIdx.y;
  const int l31 = lane & 31, lh = lane >> 5;
  const u16* qTh = qT + (size_t)h * (4096 * 32);
  const u16* kTh = kT + (size_t)h * (4096 * 32);
  const u16* vh = vv + (size_t)h * (32 * 4096);

  // zero the block reduction accumulator (must complete before any wave's atomics)
#pragma unroll
  for (int i = tid; i < 32 * 64 + 64; i += 512) red[i] = 0.0f;
  __syncthreads();

  // Q fragments (B-operand: col i = l31, k c = m*16+lh*8+e); pre-scaled by SCALE*log2e
  bf16x8 qf[2][2];
#pragma unroll
  for (int it = 0; it < 2; ++it) {
    int i = qb * 64 + it * 32 + l31;
#pragma unroll
    for (int m = 0; m < 2; ++m) qf[it][m] = ldfrag(qTh + (size_t)i * 32 + m * 16 + lh * 8);
  }

  f32x16 oacc0 = zero16(), oacc1 = zero16();
  float lsum0 = 0.0f, lsum1 = 0.0f;
  const int kvbase = s * 512;

  // direct global fragment loads: K row j = kv0+l31 (64B rows), V row c = l31 (8KB rows)
  auto loadKV = [&](int kv0, bf16x8* kf, bf16x8* vf) {
    const u16* kp = kTh + (size_t)(kv0 + l31) * 32 + lh * 8;
    kf[0] = ldfrag(kp);
    kf[1] = ldfrag(kp + 16);
    const u16* vp = vh + (size_t)l31 * 4096 + kv0 + lh * 8;
    vf[0] = ldfrag(vp);
    vf[1] = ldfrag(vp + 16);
  };

  auto compute = [&](bf16x8* kf, bf16x8* vf) {
#pragma unroll
    for (int it = 0; it < 2; ++it) {
      f32x16 sT = zero16();
      sT = MFMA32(kf[0], qf[it][0], sT);  // S^T[j][i] in log2 units
      sT = MFMA32(kf[1], qf[it][1], sT);
      float p[16];
#pragma unroll
      for (int r = 0; r < 16; ++r) p[r] = EXP2(sT[r]);
      float t0 = (p[0] + p[1]) + (p[2] + p[3]);
      float t1 = (p[4] + p[5]) + (p[6] + p[7]);
      float t2 = (p[8] + p[9]) + (p[10] + p[11]);
      float t3 = (p[12] + p[13]) + (p[14] + p[15]);
      float lloc = (t0 + t1) + (t2 + t3);
      if (it == 0) lsum0 += lloc;
      else lsum1 += lloc;
      u32 pk_[8];
#pragma unroll
      for (int m = 0; m < 8; ++m) pk_[m] = pk2(p[2 * m], p[2 * m + 1]);
      u32 ax = pk_[0], bx = pk_[2];
      plswap(ax, bx);
      u32 ay = pk_[1], by = pk_[3];
      plswap(ay, by);
      u32 cx = pk_[4], dx = pk_[6];
      plswap(cx, dx);
      u32 cy = pk_[5], dy = pk_[7];
      plswap(cy, dy);
      u32x4v f1, f2;
      f1.x = ax; f1.y = ay; f1.z = bx; f1.w = by;
      f2.x = cx; f2.y = cy; f2.z = dx; f2.w = dy;
      if (it == 0) {
        oacc0 = MFMA32(vf[0], __builtin_bit_cast(bf16x8, f1), oacc0);  // out^T[c][i]
        oacc0 = MFMA32(vf[1], __builtin_bit_cast(bf16x8, f2), oacc0);
      } else {
        oacc1 = MFMA32(vf[0], __builtin_bit_cast(bf16x8, f1), oacc1);
        oacc1 = MFMA32(vf[1], __builtin_bit_cast(bf16x8, f2), oacc1);
      }
    }
  };

  bf16x8 kA[2], vA[2], kB[2], vB[2];
  loadKV(kvbase, kA, vA);
  for (int tt = 0; tt < 16; tt += 2) {
    loadKV(kvbase + (tt + 1) * 32, kB, vB);
    compute(kA, vA);
    if (tt + 2 < 16) loadKV(kvbase + (tt + 2) * 32, kA, vA);
    compute(kB, vB);
  }

  // accumulate kv-split partials into the block accumulator (ds_add_f32)
#pragma unroll
  for (int r = 0; r < 16; ++r) {
    int c = (r & 3) + 8 * (r >> 2) + 4 * lh;
    unsafeAtomicAdd(&pbuf[c * 64 + l31], oacc0[r]);
    unsafeAtomicAdd(&pbuf[c * 64 + 32 + l31], oacc1[r]);
  }
  unsafeAtomicAdd(&lbuf[l31], lsum0);
  unsafeAtomicAdd(&lbuf[32 + l31], lsum1);
  __syncthreads();

  // normalize, store attnout[n][256] bf16
  {
    int i = tid >> 3, c0 = (tid & 7) << 2;
    float inv = 1.0f / lbuf[i];
    u32x2v ov;
    ov.x = pk2(pbuf[(c0 + 0) * 64 + i] * inv, pbuf[(c0 + 1) * 64 + i] * inv);
    ov.y = pk2(pbuf[(c0 + 2) * 64 + i] * inv, pbuf[(c0 + 3) * 64 + i] * inv);
    *(u32x2v*)(aout + (size_t)(qb * 64 + i) * 256 + h * 32 + c0) = ov;
  }
}

// ---------------- K3: out = w_out(256x256) @ attnout^T + b, fp32 output [256][4096] ----------------
// grid (64 nb, 4 db); 256 thr = 4 waves, wave w -> d-strip w*16
__global__ __launch_bounds__(256) void out_proj(const float* __restrict__ wo,
                                                const float* __restrict__ bo,
                                                const u16* __restrict__ aout,
                                                float* __restrict__ out) {
  __shared__ __align__(16) u16 Al[64 * 64];
  __shared__ __align__(16) u16 Bl[64 * 64];
  const int t = threadIdx.x;
  const int lane = t & 63, w = t >> 6;
  const int n0 = blockIdx.x * 64, d0 = blockIdx.y * 64;
  const int lr = lane & 15, lg = lane >> 4;
  f32x4 acc[4];
#pragma unroll
  for (int ni = 0; ni < 4; ++ni)
#pragma unroll
    for (int r = 0; r < 4; ++r) acc[ni][r] = 0.0f;

  for (int kc = 0; kc < 256; kc += 64) {
#pragma unroll
    for (int r = 0; r < 4; ++r) {
      int idx = r * 256 + t;
      int d = idx >> 4, c4 = (idx & 15) << 2;
      float4 v4 = *(const float4*)(wo + (size_t)(d0 + d) * 256 + kc + c4);
      u32x2v pkd;
      pkd.x = pk2(v4.x, v4.y);
      pkd.y = pk2(v4.z, v4.w);
      *(u32x2v*)&Al[d * 64 + (c4 ^ ((d & 7) << 3))] = pkd;
    }
#pragma unroll
    for (int q = 0; q < 2; ++q) {
      int nrow = q * 32 + w * 8 + (lane >> 3);
      int cb = ((lane & 7) << 4) ^ ((nrow & 7) << 4);
      gload_lds16((const char*)aout + (size_t)(n0 + nrow) * 512 + kc * 2 + cb,
                  (void*)&Bl[(q * 32 + w * 8) * 64]);
    }
    __syncthreads();
#pragma unroll
    for (int kk = 0; kk < 2; ++kk) {
      int arow = w * 16 + lr;
      bf16x8 af = ldfrag(&Al[arow * 64 + ((kk * 32 + lg * 8) ^ ((arow & 7) << 3))]);
#pragma unroll
      for (int ni = 0; ni < 4; ++ni) {
        int brow = ni * 16 + lr;
        bf16x8 bfr = ldfrag(&Bl[brow * 64 + ((kk * 32 + lg * 8) ^ ((brow & 7) << 3))]);
        acc[ni] = MFMA16(af, bfr, acc[ni]);
      }
    }
    __syncthreads();
  }
#pragma unroll
  for (int ni = 0; ni < 4; ++ni) {
    int n = n0 + ni * 16 + lr;
#pragma unroll
    for (int r = 0; r < 4; ++r) {
      int d = d0 + w * 16 + lg * 4 + r;
      out[(size_t)d * 4096 + n] = acc[ni][r] + bo[d];
    }
  }
}

extern "C" void kernel_launch(void* const* d_in, const int* in_sizes, int n_in,
                              void* d_out, int out_size, void* d_ws, size_t ws_size,
                              hipStream_t stream) {
  (void)in_sizes; (void)n_in; (void)out_size; (void)ws_size;
  const float* x = (const float*)d_in[0];
  const float* wqkv = (const float*)d_in[1];
  const float* wout = (const float*)d_in[2];
  const float* bout = (const float*)d_in[3];
  float* out = (float*)d_out;
  u16* qT = (u16*)d_ws;            // [8][4096][32]
  u16* kT = qT + 8 * 4096 * 32;    // [8][4096][32]
  u16* vv = kT + 8 * 4096 * 32;    // [8][32][4096]
  u16* aout = vv + 8 * 32 * 4096;  // [4096][256]

  qkv_gemm<<<dim3(32, 12), 256, 0, stream>>>(x, wqkv, qT, kT, vv);
  attn_fused<<<dim3(64, 8), 512, 0, stream>>>(qT, kT, vv, aout);
  out_proj<<<dim3(64, 4), 256, 0, stream>>>(wout, bout, aout, out);
}

// Round 6
// 55.787 us; speedup vs baseline: 2.0114x; 2.0114x over previous
//
#include <hip/hip_runtime.h>
#include <hip/hip_bf16.h>
#include <cstdint>

// SpatialAttention: x[1,256,16,16,16] -> qkv(768x256) -> 8-head attn(d=32, n=4096) -> proj(256x256)+bias
// ws (bf16): qT[8][4096][32] @0 (pre-scaled by SCALE*log2e), kT[8][4096][32] @2MB,
//            v[8][32][4096] @4MB, attnout[4096][256] @6MB

typedef __bf16 bf16x8 __attribute__((ext_vector_type(8)));
typedef float f32x4 __attribute__((ext_vector_type(4)));
typedef float f32x16 __attribute__((ext_vector_type(16)));
typedef unsigned int u32;
typedef unsigned short u16;
typedef u32 u32x4v __attribute__((ext_vector_type(4)));
typedef u32 u32x2v __attribute__((ext_vector_type(2)));

#define MFMA16(a, b, c) __builtin_amdgcn_mfma_f32_16x16x32_bf16(a, b, c, 0, 0, 0)
#define MFMA32(a, b, c) __builtin_amdgcn_mfma_f32_32x32x16_bf16(a, b, c, 0, 0, 0)

#if __has_builtin(__builtin_amdgcn_exp2f)
#define EXP2(x) __builtin_amdgcn_exp2f(x)
#else
#define EXP2(x) exp2f(x)
#endif

__device__ __forceinline__ u16 f2bf(float f) {
  __bf16 b = (__bf16)f;
  return __builtin_bit_cast(u16, b);
}
__device__ __forceinline__ u32 pk2(float a, float b) {
  return (u32)f2bf(a) | ((u32)f2bf(b) << 16);
}
__device__ __forceinline__ bf16x8 ldfrag(const u16* p) {
  return __builtin_bit_cast(bf16x8, *(const u32x4v*)p);
}
__device__ __forceinline__ void gload_lds16(const void* g, void* l) {
  __builtin_amdgcn_global_load_lds((const __attribute__((address_space(1))) u32*)g,
                                   (__attribute__((address_space(3))) u32*)l, 16, 0, 0);
}
// v_permlane32_swap_b32: a = {a.lo, b.lo}, b = {a.hi, b.hi}
__device__ __forceinline__ void plswap(u32& a, u32& b) {
  asm("v_permlane32_swap_b32 %0, %1" : "+v"(a), "+v"(b));
}
__device__ __forceinline__ f32x16 zero16() {
  f32x16 z;
#pragma unroll
  for (int i = 0; i < 16; ++i) z[i] = 0.0f;
  return z;
}

#if __has_builtin(__builtin_amdgcn_fdot2_f32_bf16)
typedef __bf16 bf16x2 __attribute__((ext_vector_type(2)));
__device__ __forceinline__ float dot2one(u32 pk, float acc) {
  const u32 one2 = 0x3F803F80u;  // {1.0bf, 1.0bf}
  return __builtin_amdgcn_fdot2_f32_bf16(__builtin_bit_cast(bf16x2, pk),
                                         __builtin_bit_cast(bf16x2, one2), acc, false);
}
#define LSUM_STEP(LSUM, P, PK)                               \
  {                                                          \
    _Pragma("unroll") for (int m_ = 0; m_ < 8; ++m_) LSUM =  \
        dot2one(PK[m_], LSUM);                               \
  }
#else
#define LSUM_STEP(LSUM, P, PK)                               \
  {                                                          \
    float t0_ = (P[0] + P[1]) + (P[2] + P[3]);               \
    float t1_ = (P[4] + P[5]) + (P[6] + P[7]);               \
    float t2_ = (P[8] + P[9]) + (P[10] + P[11]);             \
    float t3_ = (P[12] + P[13]) + (P[14] + P[15]);           \
    LSUM += (t0_ + t1_) + (t2_ + t3_);                       \
  }
#endif

// ---------------- K1: qkv = w_qkv(768x256) @ x(256x4096), LDS-staged 64o x 128n ----------------
// grid (32 nb, 12 ob), 256 thr = 4 waves: wm = w&1 (2x32o), wn = w>>1 (2x64n)
__global__ __launch_bounds__(256) void qkv_gemm(const float* __restrict__ x,
                                                const float* __restrict__ wq,
                                                u16* __restrict__ qT, u16* __restrict__ kT,
                                                u16* __restrict__ vv) {
  __shared__ __align__(16) u16 Al[64 * 64];
  __shared__ __align__(16) u16 Bl[128 * 64];
  const int t = threadIdx.x;
  const int lane = t & 63, w = t >> 6;
  const int wm = w & 1, wn = w >> 1;
  const int o0 = blockIdx.y * 64, n0 = blockIdx.x * 128;
  const int lr = lane & 15, lg = lane >> 4;
  const float sc = (o0 < 256) ? 0.2550349f : 1.0f;  // q tile: 32^-0.5 * log2(e); uniform per block
  f32x4 acc[2][4];
#pragma unroll
  for (int i = 0; i < 2; ++i)
#pragma unroll
    for (int j = 0; j < 4; ++j)
#pragma unroll
      for (int r = 0; r < 4; ++r) acc[i][j][r] = 0.0f;

  for (int kc = 0; kc < 256; kc += 64) {
    // stage A = w_qkv tile [64 o][64 c], fp32->bf16, scaled
#pragma unroll
    for (int r = 0; r < 4; ++r) {
      int idx = r * 256 + t;
      int o = idx >> 4, c4 = (idx & 15) << 2;
      float4 v4 = *(const float4*)(wq + (size_t)(o0 + o) * 256 + kc + c4);
      u32x2v pkd;
      pkd.x = pk2(v4.x * sc, v4.y * sc);
      pkd.y = pk2(v4.z * sc, v4.w * sc);
      *(u32x2v*)&Al[o * 64 + (c4 ^ ((o & 7) << 3))] = pkd;
    }
    // stage B = x tile transposed to [128 n][64 c]; per-lane 4 channels of one n, packed 8B write
#pragma unroll
    for (int r = 0; r < 8; ++r) {
      int idx = r * 256 + t;
      int n = idx & 127, cg = idx >> 7;
      int c4 = cg << 2;
      const float* xb = x + (size_t)(kc + c4) * 4096 + n0 + n;
      float a0 = xb[0], a1 = xb[4096], a2 = xb[8192], a3 = xb[12288];
      u32x2v pkd;
      pkd.x = pk2(a0, a1);
      pkd.y = pk2(a2, a3);
      *(u32x2v*)&Bl[n * 64 + (c4 ^ ((n & 7) << 3))] = pkd;
    }
    __syncthreads();
#pragma unroll
    for (int kk = 0; kk < 2; ++kk) {
      bf16x8 af[2], bf_[4];
#pragma unroll
      for (int mi = 0; mi < 2; ++mi) {
        int row = wm * 32 + mi * 16 + lr;
        af[mi] = ldfrag(&Al[row * 64 + ((kk * 32 + lg * 8) ^ ((row & 7) << 3))]);
      }
#pragma unroll
      for (int ni = 0; ni < 4; ++ni) {
        int row = wn * 64 + ni * 16 + lr;
        bf_[ni] = ldfrag(&Bl[row * 64 + ((kk * 32 + lg * 8) ^ ((row & 7) << 3))]);
      }
#pragma unroll
      for (int mi = 0; mi < 2; ++mi)
#pragma unroll
        for (int ni = 0; ni < 4; ++ni) acc[mi][ni] = MFMA16(af[mi], bf_[ni], acc[mi][ni]);
    }
    __syncthreads();
  }
  // epilogue: D[o][n]; col n = lr, rows o = obase + r; scatter to q/k/v layouts
#pragma unroll
  for (int mi = 0; mi < 2; ++mi) {
#pragma unroll
    for (int ni = 0; ni < 4; ++ni) {
      int obase = o0 + wm * 32 + mi * 16 + lg * 4;
      int n = n0 + wn * 64 + ni * 16 + lr;
      int part = obase >> 8;
      int oin = obase & 255;
      int h = oin >> 5, c0 = oin & 31;
      if (part == 0) {
        u32x2v pv;
        pv.x = pk2(acc[mi][ni][0], acc[mi][ni][1]);
        pv.y = pk2(acc[mi][ni][2], acc[mi][ni][3]);
        *(u32x2v*)(qT + ((size_t)h * 4096 + n) * 32 + c0) = pv;
      } else if (part == 1) {
        u32x2v pv;
        pv.x = pk2(acc[mi][ni][0], acc[mi][ni][1]);
        pv.y = pk2(acc[mi][ni][2], acc[mi][ni][3]);
        *(u32x2v*)(kT + ((size_t)h * 4096 + n) * 32 + c0) = pv;
      } else {
#pragma unroll
        for (int r = 0; r < 4; ++r)
          vv[((size_t)h * 32 + c0 + r) * 4096 + n] = f2bf(acc[mi][ni][r]);
      }
    }
  }
}

// ---------------- K2: fused flash attention, direct-global fragments, macro-inlined --------------
// grid (64 qb, 8 h); 512 thr = 8 waves; wave s: 64 q x kv [s*512, s*512+512)
// K/V fragments loaded straight from global (L2-resident); LDS only for the split reduction.

#define LOAD_TILE(KV0, K0, K1, V0, V1)                            \
  do {                                                            \
    const u16* kp_ = kTh + (size_t)((KV0) + l31) * 32 + lh * 8;   \
    K0 = ldfrag(kp_);                                             \
    K1 = ldfrag(kp_ + 16);                                        \
    const u16* vp_ = vh + (size_t)l31 * 4096 + (KV0) + lh * 8;    \
    V0 = ldfrag(vp_);                                             \
    V1 = ldfrag(vp_ + 16);                                        \
  } while (0)

#define COMPUTE_IT(QF0, QF1, OACC, LSUM, K0, K1, V0, V1)                      \
  do {                                                                        \
    f32x16 sT_ = zero16();                                                    \
    sT_ = MFMA32(K0, QF0, sT_); /* S^T[j][i] in log2 units */                 \
    sT_ = MFMA32(K1, QF1, sT_);                                               \
    float p_[16];                                                             \
    _Pragma("unroll") for (int r_ = 0; r_ < 16; ++r_) p_[r_] = EXP2(sT_[r_]); \
    u32 pkv_[8];                                                              \
    _Pragma("unroll") for (int m_ = 0; m_ < 8; ++m_) pkv_[m_] =               \
        pk2(p_[2 * m_], p_[2 * m_ + 1]);                                      \
    LSUM_STEP(LSUM, p_, pkv_)                                                 \
    u32 ax_ = pkv_[0], bx_ = pkv_[2];                                         \
    plswap(ax_, bx_);                                                         \
    u32 ay_ = pkv_[1], by_ = pkv_[3];                                         \
    plswap(ay_, by_);                                                         \
    u32 cx_ = pkv_[4], dx_ = pkv_[6];                                         \
    plswap(cx_, dx_);                                                         \
    u32 cy_ = pkv_[5], dy_ = pkv_[7];                                         \
    plswap(cy_, dy_);                                                         \
    u32x4v f1_, f2_;                                                          \
    f1_.x = ax_; f1_.y = ay_; f1_.z = bx_; f1_.w = by_;                       \
    f2_.x = cx_; f2_.y = cy_; f2_.z = dx_; f2_.w = dy_;                       \
    OACC = MFMA32(V0, __builtin_bit_cast(bf16x8, f1_), OACC);                 \
    OACC = MFMA32(V1, __builtin_bit_cast(bf16x8, f2_), OACC);                 \
  } while (0)

__global__ __launch_bounds__(512, 4) void attn_fused(const u16* __restrict__ qT,
                                                     const u16* __restrict__ kT,
                                                     const u16* __restrict__ vv,
                                                     u16* __restrict__ aout) {
  __shared__ float pbuf[8 * 32 * 66];  // [8 s][32 c][64 i + 2 pad]
  __shared__ float lbuf[8 * 64];       // [8 s][64 i]
  const int tid = threadIdx.x;
  const int lane = tid & 63, s = tid >> 6;
  const int qb = blockIdx.x, h = blockIdx.y;
  const int l31 = lane & 31, lh = lane >> 5;
  const u16* qTh = qT + (size_t)h * (4096 * 32);
  const u16* kTh = kT + (size_t)h * (4096 * 32);
  const u16* vh = vv + (size_t)h * (32 * 4096);

  // Q fragments (B-operand: col i = l31, k c = m*16+lh*8+e); pre-scaled by SCALE*log2e
  const int i0 = qb * 64 + l31;
  bf16x8 qf00 = ldfrag(qTh + (size_t)i0 * 32 + lh * 8);
  bf16x8 qf01 = ldfrag(qTh + (size_t)i0 * 32 + 16 + lh * 8);
  bf16x8 qf10 = ldfrag(qTh + (size_t)(i0 + 32) * 32 + lh * 8);
  bf16x8 qf11 = ldfrag(qTh + (size_t)(i0 + 32) * 32 + 16 + lh * 8);

  f32x16 oacc0 = zero16(), oacc1 = zero16();
  float lsum0 = 0.0f, lsum1 = 0.0f;
  const int kvbase = s * 512;

  bf16x8 ka0, ka1, va0, va1, kb0, kb1, vb0, vb1;
  LOAD_TILE(kvbase, ka0, ka1, va0, va1);
  for (int tt = 0; tt < 16; tt += 2) {
    LOAD_TILE(kvbase + (tt + 1) * 32, kb0, kb1, vb0, vb1);
    COMPUTE_IT(qf00, qf01, oacc0, lsum0, ka0, ka1, va0, va1);
    COMPUTE_IT(qf10, qf11, oacc1, lsum1, ka0, ka1, va0, va1);
    if (tt + 2 < 16) LOAD_TILE(kvbase + (tt + 2) * 32, ka0, ka1, va0, va1);
    COMPUTE_IT(qf00, qf01, oacc0, lsum0, kb0, kb1, vb0, vb1);
    COMPUTE_IT(qf10, qf11, oacc1, lsum1, kb0, kb1, vb0, vb1);
  }

  // per-wave partials to LDS (disjoint slots, no atomics)
  float ls0 = lsum0 + __shfl_xor(lsum0, 32, 64);
  float ls1 = lsum1 + __shfl_xor(lsum1, 32, 64);
#pragma unroll
  for (int r = 0; r < 16; ++r) {
    int c = (r & 3) + 8 * (r >> 2) + 4 * lh;
    pbuf[(s * 32 + c) * 66 + l31] = oacc0[r];
    pbuf[(s * 32 + c) * 66 + 32 + l31] = oacc1[r];
  }
  lbuf[s * 64 + l31] = ls0;
  lbuf[s * 64 + 32 + l31] = ls1;
  __syncthreads();

  // reduce 8 kv-split partials, normalize, store attnout[n][256] bf16
  {
    int i = tid >> 3, c0 = (tid & 7) << 2;
    float lt = 0.0f;
#pragma unroll
    for (int ss = 0; ss < 8; ++ss) lt += lbuf[ss * 64 + i];
    float inv = 1.0f / lt;
    float a[4];
#pragma unroll
    for (int cc = 0; cc < 4; ++cc) a[cc] = 0.0f;
#pragma unroll
    for (int ss = 0; ss < 8; ++ss)
#pragma unroll
      for (int cc = 0; cc < 4; ++cc) a[cc] += pbuf[(ss * 32 + c0 + cc) * 66 + i];
    u32x2v ov;
    ov.x = pk2(a[0] * inv, a[1] * inv);
    ov.y = pk2(a[2] * inv, a[3] * inv);
    *(u32x2v*)(aout + (size_t)(qb * 64 + i) * 256 + h * 32 + c0) = ov;
  }
}

// ---------------- K3: out = w_out(256x256) @ attnout^T + b, fp32 output [256][4096] ----------------
// grid (64 nb, 4 db); 256 thr = 4 waves, wave w -> d-strip w*16
__global__ __launch_bounds__(256) void out_proj(const float* __restrict__ wo,
                                                const float* __restrict__ bo,
                                                const u16* __restrict__ aout,
                                                float* __restrict__ out) {
  __shared__ __align__(16) u16 Al[64 * 64];
  __shared__ __align__(16) u16 Bl[64 * 64];
  const int t = threadIdx.x;
  const int lane = t & 63, w = t >> 6;
  const int n0 = blockIdx.x * 64, d0 = blockIdx.y * 64;
  const int lr = lane & 15, lg = lane >> 4;
  f32x4 acc[4];
#pragma unroll
  for (int ni = 0; ni < 4; ++ni)
#pragma unroll
    for (int r = 0; r < 4; ++r) acc[ni][r] = 0.0f;

  for (int kc = 0; kc < 256; kc += 64) {
#pragma unroll
    for (int r = 0; r < 4; ++r) {
      int idx = r * 256 + t;
      int d = idx >> 4, c4 = (idx & 15) << 2;
      float4 v4 = *(const float4*)(wo + (size_t)(d0 + d) * 256 + kc + c4);
      u32x2v pkd;
      pkd.x = pk2(v4.x, v4.y);
      pkd.y = pk2(v4.z, v4.w);
      *(u32x2v*)&Al[d * 64 + (c4 ^ ((d & 7) << 3))] = pkd;
    }
#pragma unroll
    for (int q = 0; q < 2; ++q) {
      int nrow = q * 32 + w * 8 + (lane >> 3);
      int cb = ((lane & 7) << 4) ^ ((nrow & 7) << 4);
      gload_lds16((const char*)aout + (size_t)(n0 + nrow) * 512 + kc * 2 + cb,
                  (void*)&Bl[(q * 32 + w * 8) * 64]);
    }
    __syncthreads();
#pragma unroll
    for (int kk = 0; kk < 2; ++kk) {
      int arow = w * 16 + lr;
      bf16x8 af = ldfrag(&Al[arow * 64 + ((kk * 32 + lg * 8) ^ ((arow & 7) << 3))]);
#pragma unroll
      for (int ni = 0; ni < 4; ++ni) {
        int brow = ni * 16 + lr;
        bf16x8 bfr = ldfrag(&Bl[brow * 64 + ((kk * 32 + lg * 8) ^ ((brow & 7) << 3))]);
        acc[ni] = MFMA16(af, bfr, acc[ni]);
      }
    }
    __syncthreads();
  }
#pragma unroll
  for (int ni = 0; ni < 4; ++ni) {
    int n = n0 + ni * 16 + lr;
#pragma unroll
    for (int r = 0; r < 4; ++r) {
      int d = d0 + w * 16 + lg * 4 + r;
      out[(size_t)d * 4096 + n] = acc[ni][r] + bo[d];
    }
  }
}

extern "C" void kernel_launch(void* const* d_in, const int* in_sizes, int n_in,
                              void* d_out, int out_size, void* d_ws, size_t ws_size,
                              hipStream_t stream) {
  (void)in_sizes; (void)n_in; (void)out_size; (void)ws_size;
  const float* x = (const float*)d_in[0];
  const float* wqkv = (const float*)d_in[1];
  const float* wout = (const float*)d_in[2];
  const float* bout = (const float*)d_in[3];
  float* out = (float*)d_out;
  u16* qT = (u16*)d_ws;            // [8][4096][32]
  u16* kT = qT + 8 * 4096 * 32;    // [8][4096][32]
  u16* vv = kT + 8 * 4096 * 32;    // [8][32][4096]
  u16* aout = vv + 8 * 32 * 4096;  // [4096][256]

  qkv_gemm<<<dim3(32, 12), 256, 0, stream>>>(x, wqkv, qT, kT, vv);
  attn_fused<<<dim3(64, 8), 512, 0, stream>>>(qT, kT, vv, aout);
  out_proj<<<dim3(64, 4), 256, 0, stream>>>(wout, bout, aout, out);
}

// Round 7
// 52.676 us; speedup vs baseline: 2.1302x; 1.0591x over previous
//
#include <hip/hip_runtime.h>
#include <hip/hip_bf16.h>
#include <cstdint>

// SpatialAttention: x[1,256,16,16,16] -> qkv(768x256) -> 8-head attn(d=32, n=4096) -> proj(256x256)+bias
// ws (u16 units): qT[8][4096][32] @0 (pre-scaled by SCALE*log2e), kT @1M, vv[8][32][4096] @2M,
//                 aout[4096][256] @3M, xT[4096][256] @4M, wqb[768][256] @5M, wob[256][256] @5M+192K

typedef __bf16 bf16x8 __attribute__((ext_vector_type(8)));
typedef float f32x4 __attribute__((ext_vector_type(4)));
typedef float f32x16 __attribute__((ext_vector_type(16)));
typedef unsigned int u32;
typedef unsigned short u16;
typedef u32 u32x4v __attribute__((ext_vector_type(4)));
typedef u32 u32x2v __attribute__((ext_vector_type(2)));

#define MFMA16(a, b, c) __builtin_amdgcn_mfma_f32_16x16x32_bf16(a, b, c, 0, 0, 0)
#define MFMA32(a, b, c) __builtin_amdgcn_mfma_f32_32x32x16_bf16(a, b, c, 0, 0, 0)

#if __has_builtin(__builtin_amdgcn_exp2f)
#define EXP2(x) __builtin_amdgcn_exp2f(x)
#else
#define EXP2(x) exp2f(x)
#endif

__device__ __forceinline__ u16 f2bf(float f) {
  __bf16 b = (__bf16)f;
  return __builtin_bit_cast(u16, b);
}
__device__ __forceinline__ u32 pk2(float a, float b) {
  return (u32)f2bf(a) | ((u32)f2bf(b) << 16);
}
__device__ __forceinline__ bf16x8 ldfrag(const u16* p) {
  return __builtin_bit_cast(bf16x8, *(const u32x4v*)p);
}
__device__ __forceinline__ void gload_lds16(const void* g, void* l) {
  __builtin_amdgcn_global_load_lds((const __attribute__((address_space(1))) u32*)g,
                                   (__attribute__((address_space(3))) u32*)l, 16, 0, 0);
}
// v_permlane32_swap_b32: a = {a.lo, b.lo}, b = {a.hi, b.hi}
__device__ __forceinline__ void plswap(u32& a, u32& b) {
  asm("v_permlane32_swap_b32 %0, %1" : "+v"(a), "+v"(b));
}
__device__ __forceinline__ f32x16 zero16() {
  f32x16 z;
#pragma unroll
  for (int i = 0; i < 16; ++i) z[i] = 0.0f;
  return z;
}

#if __has_builtin(__builtin_amdgcn_fdot2_f32_bf16)
typedef __bf16 bf16x2 __attribute__((ext_vector_type(2)));
__device__ __forceinline__ float dot2one(u32 pk, float acc) {
  const u32 one2 = 0x3F803F80u;  // {1.0bf, 1.0bf}
  return __builtin_amdgcn_fdot2_f32_bf16(__builtin_bit_cast(bf16x2, pk),
                                         __builtin_bit_cast(bf16x2, one2), acc, false);
}
#define LSUM_STEP(LSUM, P, PK)                               \
  {                                                          \
    _Pragma("unroll") for (int m_ = 0; m_ < 8; ++m_) LSUM =  \
        dot2one(PK[m_], LSUM);                               \
  }
#else
#define LSUM_STEP(LSUM, P, PK)                               \
  {                                                          \
    float t0_ = (P[0] + P[1]) + (P[2] + P[3]);               \
    float t1_ = (P[4] + P[5]) + (P[6] + P[7]);               \
    float t2_ = (P[8] + P[9]) + (P[10] + P[11]);             \
    float t3_ = (P[12] + P[13]) + (P[14] + P[15]);           \
    LSUM += (t0_ + t1_) + (t2_ + t3_);                       \
  }
#endif

// ---------------- K0: prep — x transpose to xT bf16, w_qkv->bf16 (q-scaled), w_out->bf16 --------
// grid 320 x 256: blocks 0..255 transpose, 256..303 w_qkv, 304..319 w_out
__global__ __launch_bounds__(256) void prep(const float* __restrict__ x,
                                            const float* __restrict__ wq,
                                            const float* __restrict__ wo,
                                            u16* __restrict__ xT, u16* __restrict__ wqb,
                                            u16* __restrict__ wob) {
  const int b = blockIdx.x;
  const int t = threadIdx.x;
  if (b < 256) {
    __shared__ u16 tile[64][72];
    const int n0 = (b & 63) * 64, c0 = (b >> 6) * 64;
#pragma unroll
    for (int r = 0; r < 4; ++r) {
      int c = r * 16 + (t >> 4);
      int n4 = (t & 15) << 2;
      float4 v = *(const float4*)(x + (size_t)(c0 + c) * 4096 + n0 + n4);
      tile[n4 + 0][c] = f2bf(v.x);
      tile[n4 + 1][c] = f2bf(v.y);
      tile[n4 + 2][c] = f2bf(v.z);
      tile[n4 + 3][c] = f2bf(v.w);
    }
    __syncthreads();
#pragma unroll
    for (int r2 = 0; r2 < 2; ++r2) {
      int n = r2 * 32 + (t >> 3);
      int c8 = (t & 7) << 3;
      u32x4v o;
#pragma unroll
      for (int j = 0; j < 4; ++j)
        o[j] = (u32)tile[n][c8 + 2 * j] | ((u32)tile[n][c8 + 2 * j + 1] << 16);
      *(u32x4v*)(xT + (size_t)(n0 + n) * 256 + c0 + c8) = o;
    }
  } else if (b < 304) {
    int base = (b - 256) * 4096;
#pragma unroll
    for (int r = 0; r < 4; ++r) {
      int i = base + r * 1024 + t * 4;
      float4 v = *(const float4*)(wq + i);
      float sc = (i < 65536) ? 0.2550349f : 1.0f;  // q rows: 32^-0.5 * log2(e)
      u32x2v pkd;
      pkd.x = pk2(v.x * sc, v.y * sc);
      pkd.y = pk2(v.z * sc, v.w * sc);
      *(u32x2v*)(wqb + i) = pkd;
    }
  } else {
    int base = (b - 304) * 4096;
#pragma unroll
    for (int r = 0; r < 4; ++r) {
      int i = base + r * 1024 + t * 4;
      float4 v = *(const float4*)(wo + i);
      u32x2v pkd;
      pkd.x = pk2(v.x, v.y);
      pkd.y = pk2(v.z, v.w);
      *(u32x2v*)(wob + i) = pkd;
    }
  }
}

// ---------------- K1: qkv = wqb(768x256) @ xT^T, all-gload_lds staging, scatter to qT/kT/vv -----
// grid (64 nb, 12 ob), 256 thr = 4 waves: wm=w&1, wn=w>>1 -> 32o x 32n per wave
__global__ __launch_bounds__(256) void qkv_gemm(const u16* __restrict__ xT,
                                                const u16* __restrict__ wqb,
                                                u16* __restrict__ qT, u16* __restrict__ kT,
                                                u16* __restrict__ vv) {
  __shared__ __align__(16) u16 Al[64 * 64];
  __shared__ __align__(16) u16 Bl[64 * 64];
  const int t = threadIdx.x;
  const int lane = t & 63, w = t >> 6;
  const int wm = w & 1, wn = w >> 1;
  const int o0 = blockIdx.y * 64, n0 = blockIdx.x * 64;
  const int lr = lane & 15, lg = lane >> 4;
  const int srow = lane >> 3, sslot = lane & 7;
  f32x4 acc[2][2];
#pragma unroll
  for (int i = 0; i < 2; ++i)
#pragma unroll
    for (int j = 0; j < 2; ++j)
#pragma unroll
      for (int r = 0; r < 4; ++r) acc[i][j][r] = 0.0f;

  for (int kc = 0; kc < 256; kc += 64) {
    // stage A=wqb tile [64 o][64 c], B=xT tile [64 n][64 c]; linear LDS dest, pre-swizzled src
#pragma unroll
    for (int rnd = 0; rnd < 2; ++rnd) {
      int row = rnd * 32 + w * 8 + srow;
      gload_lds16(wqb + (size_t)(o0 + row) * 256 + kc + ((sslot ^ (row & 7)) << 3),
                  (void*)(Al + rnd * 2048 + w * 512));
      gload_lds16(xT + (size_t)(n0 + row) * 256 + kc + ((sslot ^ (row & 7)) << 3),
                  (void*)(Bl + rnd * 2048 + w * 512));
    }
    __syncthreads();
#pragma unroll
    for (int kk = 0; kk < 2; ++kk) {
      bf16x8 af[2], bf_[2];
#pragma unroll
      for (int mi = 0; mi < 2; ++mi) {
        int row = wm * 32 + mi * 16 + lr;
        af[mi] = ldfrag(&Al[row * 64 + ((kk * 32 + lg * 8) ^ ((row & 7) << 3))]);
      }
#pragma unroll
      for (int ni = 0; ni < 2; ++ni) {
        int row = wn * 32 + ni * 16 + lr;
        bf_[ni] = ldfrag(&Bl[row * 64 + ((kk * 32 + lg * 8) ^ ((row & 7) << 3))]);
      }
#pragma unroll
      for (int mi = 0; mi < 2; ++mi)
#pragma unroll
        for (int ni = 0; ni < 2; ++ni) acc[mi][ni] = MFMA16(af[mi], bf_[ni], acc[mi][ni]);
    }
    __syncthreads();
  }
  // epilogue: D[o][n]; col n = lr, rows o = obase + r; scatter to q/k/v layouts
#pragma unroll
  for (int mi = 0; mi < 2; ++mi) {
#pragma unroll
    for (int ni = 0; ni < 2; ++ni) {
      int obase = o0 + wm * 32 + mi * 16 + lg * 4;
      int n = n0 + wn * 32 + ni * 16 + lr;
      int part = obase >> 8;
      int oin = obase & 255;
      int h = oin >> 5, c0 = oin & 31;
      if (part == 0) {
        u32x2v pv;
        pv.x = pk2(acc[mi][ni][0], acc[mi][ni][1]);
        pv.y = pk2(acc[mi][ni][2], acc[mi][ni][3]);
        *(u32x2v*)(qT + ((size_t)h * 4096 + n) * 32 + c0) = pv;
      } else if (part == 1) {
        u32x2v pv;
        pv.x = pk2(acc[mi][ni][0], acc[mi][ni][1]);
        pv.y = pk2(acc[mi][ni][2], acc[mi][ni][3]);
        *(u32x2v*)(kT + ((size_t)h * 4096 + n) * 32 + c0) = pv;
      } else {
#pragma unroll
        for (int r = 0; r < 4; ++r)
          vv[((size_t)h * 32 + c0 + r) * 4096 + n] = f2bf(acc[mi][ni][r]);
      }
    }
  }
}

// ---------------- K2: fused flash attention, direct-global fragments, macro-inlined --------------
// grid (64 qb, 8 h); 512 thr = 8 waves; wave s: 64 q x kv [s*512, s*512+512)

#define LOAD_TILE(KV0, K0, K1, V0, V1)                            \
  do {                                                            \
    const u16* kp_ = kTh + (size_t)((KV0) + l31) * 32 + lh * 8;   \
    K0 = ldfrag(kp_);                                             \
    K1 = ldfrag(kp_ + 16);                                        \
    const u16* vp_ = vh + (size_t)l31 * 4096 + (KV0) + lh * 8;    \
    V0 = ldfrag(vp_);                                             \
    V1 = ldfrag(vp_ + 16);                                        \
  } while (0)

#define COMPUTE_IT(QF0, QF1, OACC, LSUM, K0, K1, V0, V1)                      \
  do {                                                                        \
    f32x16 sT_ = zero16();                                                    \
    __builtin_amdgcn_s_setprio(1);                                            \
    sT_ = MFMA32(K0, QF0, sT_); /* S^T[j][i] in log2 units */                 \
    sT_ = MFMA32(K1, QF1, sT_);                                               \
    __builtin_amdgcn_s_setprio(0);                                            \
    float p_[16];                                                             \
    _Pragma("unroll") for (int r_ = 0; r_ < 16; ++r_) p_[r_] = EXP2(sT_[r_]); \
    u32 pkv_[8];                                                              \
    _Pragma("unroll") for (int m_ = 0; m_ < 8; ++m_) pkv_[m_] =               \
        pk2(p_[2 * m_], p_[2 * m_ + 1]);                                      \
    LSUM_STEP(LSUM, p_, pkv_)                                                 \
    u32 ax_ = pkv_[0], bx_ = pkv_[2];                                         \
    plswap(ax_, bx_);                                                         \
    u32 ay_ = pkv_[1], by_ = pkv_[3];                                         \
    plswap(ay_, by_);                                                         \
    u32 cx_ = pkv_[4], dx_ = pkv_[6];                                         \
    plswap(cx_, dx_);                                                         \
    u32 cy_ = pkv_[5], dy_ = pkv_[7];                                         \
    plswap(cy_, dy_);                                                         \
    u32x4v f1_, f2_;                                                          \
    f1_.x = ax_; f1_.y = ay_; f1_.z = bx_; f1_.w = by_;                       \
    f2_.x = cx_; f2_.y = cy_; f2_.z = dx_; f2_.w = dy_;                       \
    __builtin_amdgcn_s_setprio(1);                                            \
    OACC = MFMA32(V0, __builtin_bit_cast(bf16x8, f1_), OACC);                 \
    OACC = MFMA32(V1, __builtin_bit_cast(bf16x8, f2_), OACC);                 \
    __builtin_amdgcn_s_setprio(0);                                            \
  } while (0)

__global__ __launch_bounds__(512, 4) void attn_fused(const u16* __restrict__ qT,
                                                     const u16* __restrict__ kT,
                                                     const u16* __restrict__ vv,
                                                     u16* __restrict__ aout) {
  __shared__ float pbuf[8 * 32 * 66];  // [8 s][32 c][64 i + 2 pad]
  __shared__ float lbuf[8 * 64];       // [8 s][64 i]
  const int tid = threadIdx.x;
  const int lane = tid & 63, s = tid >> 6;
  const int qb = blockIdx.x, h = blockIdx.y;
  const int l31 = lane & 31, lh = lane >> 5;
  const u16* qTh = qT + (size_t)h * (4096 * 32);
  const u16* kTh = kT + (size_t)h * (4096 * 32);
  const u16* vh = vv + (size_t)h * (32 * 4096);

  // Q fragments (B-operand: col i = l31, k c = m*16+lh*8+e); pre-scaled by SCALE*log2e
  const int i0 = qb * 64 + l31;
  bf16x8 qf00 = ldfrag(qTh + (size_t)i0 * 32 + lh * 8);
  bf16x8 qf01 = ldfrag(qTh + (size_t)i0 * 32 + 16 + lh * 8);
  bf16x8 qf10 = ldfrag(qTh + (size_t)(i0 + 32) * 32 + lh * 8);
  bf16x8 qf11 = ldfrag(qTh + (size_t)(i0 + 32) * 32 + 16 + lh * 8);

  f32x16 oacc0 = zero16(), oacc1 = zero16();
  float lsum0 = 0.0f, lsum1 = 0.0f;
  const int kvbase = s * 512;

  bf16x8 ka0, ka1, va0, va1, kb0, kb1, vb0, vb1;
  LOAD_TILE(kvbase, ka0, ka1, va0, va1);
  for (int tt = 0; tt < 16; tt += 2) {
    LOAD_TILE(kvbase + (tt + 1) * 32, kb0, kb1, vb0, vb1);
    COMPUTE_IT(qf00, qf01, oacc0, lsum0, ka0, ka1, va0, va1);
    COMPUTE_IT(qf10, qf11, oacc1, lsum1, ka0, ka1, va0, va1);
    if (tt + 2 < 16) LOAD_TILE(kvbase + (tt + 2) * 32, ka0, ka1, va0, va1);
    COMPUTE_IT(qf00, qf01, oacc0, lsum0, kb0, kb1, vb0, vb1);
    COMPUTE_IT(qf10, qf11, oacc1, lsum1, kb0, kb1, vb0, vb1);
  }

  // per-wave partials to LDS (disjoint slots, no atomics)
  float ls0 = lsum0 + __shfl_xor(lsum0, 32, 64);
  float ls1 = lsum1 + __shfl_xor(lsum1, 32, 64);
#pragma unroll
  for (int r = 0; r < 16; ++r) {
    int c = (r & 3) + 8 * (r >> 2) + 4 * lh;
    pbuf[(s * 32 + c) * 66 + l31] = oacc0[r];
    pbuf[(s * 32 + c) * 66 + 32 + l31] = oacc1[r];
  }
  lbuf[s * 64 + l31] = ls0;
  lbuf[s * 64 + 32 + l31] = ls1;
  __syncthreads();

  // reduce 8 kv-split partials, normalize, store attnout[n][256] bf16
  {
    int i = tid >> 3, c0 = (tid & 7) << 2;
    float lt = 0.0f;
#pragma unroll
    for (int ss = 0; ss < 8; ++ss) lt += lbuf[ss * 64 + i];
    float inv = 1.0f / lt;
    float a[4];
#pragma unroll
    for (int cc = 0; cc < 4; ++cc) a[cc] = 0.0f;
#pragma unroll
    for (int ss = 0; ss < 8; ++ss)
#pragma unroll
      for (int cc = 0; cc < 4; ++cc) a[cc] += pbuf[(ss * 32 + c0 + cc) * 66 + i];
    u32x2v ov;
    ov.x = pk2(a[0] * inv, a[1] * inv);
    ov.y = pk2(a[2] * inv, a[3] * inv);
    *(u32x2v*)(aout + (size_t)(qb * 64 + i) * 256 + h * 32 + c0) = ov;
  }
}

// ---------------- K3: out = wob(256x256) @ attnout^T + b, fp32 output [256][4096] ----------------
// grid (64 nb, 4 db); 256 thr = 4 waves, wave w -> d-strip w*16
__global__ __launch_bounds__(256) void out_proj(const u16* __restrict__ wob,
                                                const float* __restrict__ bo,
                                                const u16* __restrict__ aout,
                                                float* __restrict__ out) {
  __shared__ __align__(16) u16 Al[64 * 64];
  __shared__ __align__(16) u16 Bl[64 * 64];
  const int t = threadIdx.x;
  const int lane = t & 63, w = t >> 6;
  const int n0 = blockIdx.x * 64, d0 = blockIdx.y * 64;
  const int lr = lane & 15, lg = lane >> 4;
  const int srow = lane >> 3, sslot = lane & 7;
  f32x4 acc[4];
#pragma unroll
  for (int ni = 0; ni < 4; ++ni)
#pragma unroll
    for (int r = 0; r < 4; ++r) acc[ni][r] = 0.0f;

  for (int kc = 0; kc < 256; kc += 64) {
#pragma unroll
    for (int rnd = 0; rnd < 2; ++rnd) {
      int row = rnd * 32 + w * 8 + srow;
      gload_lds16(wob + (size_t)(d0 + row) * 256 + kc + ((sslot ^ (row & 7)) << 3),
                  (void*)(Al + rnd * 2048 + w * 512));
      gload_lds16(aout + (size_t)(n0 + row) * 256 + kc + ((sslot ^ (row & 7)) << 3),
                  (void*)(Bl + rnd * 2048 + w * 512));
    }
    __syncthreads();
#pragma unroll
    for (int kk = 0; kk < 2; ++kk) {
      int arow = w * 16 + lr;
      bf16x8 af = ldfrag(&Al[arow * 64 + ((kk * 32 + lg * 8) ^ ((arow & 7) << 3))]);
#pragma unroll
      for (int ni = 0; ni < 4; ++ni) {
        int brow = ni * 16 + lr;
        bf16x8 bfr = ldfrag(&Bl[brow * 64 + ((kk * 32 + lg * 8) ^ ((brow & 7) << 3))]);
        acc[ni] = MFMA16(af, bfr, acc[ni]);
      }
    }
    __syncthreads();
  }
#pragma unroll
  for (int ni = 0; ni < 4; ++ni) {
    int n = n0 + ni * 16 + lr;
#pragma unroll
    for (int r = 0; r < 4; ++r) {
      int d = d0 + w * 16 + lg * 4 + r;
      out[(size_t)d * 4096 + n] = acc[ni][r] + bo[d];
    }
  }
}

extern "C" void kernel_launch(void* const* d_in, const int* in_sizes, int n_in,
                              void* d_out, int out_size, void* d_ws, size_t ws_size,
                              hipStream_t stream) {
  (void)in_sizes; (void)n_in; (void)out_size; (void)ws_size;
  const float* x = (const float*)d_in[0];
  const float* wqkv = (const float*)d_in[1];
  const float* wout = (const float*)d_in[2];
  const float* bout = (const float*)d_in[3];
  float* out = (float*)d_out;
  u16* qT = (u16*)d_ws;            // [8][4096][32]
  u16* kT = qT + 8 * 4096 * 32;    // [8][4096][32]
  u16* vv = kT + 8 * 4096 * 32;    // [8][32][4096]
  u16* aout = vv + 8 * 32 * 4096;  // [4096][256]
  u16* xT = aout + 4096 * 256;     // [4096][256]
  u16* wqb = xT + 4096 * 256;      // [768][256]
  u16* wob = wqb + 768 * 256;      // [256][256]

  prep<<<320, 256, 0, stream>>>(x, wqkv, wout, xT, wqb, wob);
  qkv_gemm<<<dim3(64, 12), 256, 0, stream>>>(xT, wqb, qT, kT, vv);
  attn_fused<<<dim3(64, 8), 512, 0, stream>>>(qT, kT, vv, aout);
  out_proj<<<dim3(64, 4), 256, 0, stream>>>(wob, bout, aout, out);
}